// Round 2
// baseline (5116.164 us; speedup 1.0000x reference)
//
#include <hip/hip_runtime.h>
#include <math.h>

// Problem constants (B=1024, N_TOK=65, C=768, H=12, D=64, L=256)
#define NT 65

typedef unsigned short u16;
typedef __attribute__((ext_vector_type(8))) short short8v;
typedef __attribute__((ext_vector_type(4))) float float4v;

__device__ __forceinline__ u16 bf16rn(float f) {
    unsigned int u = __float_as_uint(f);
    u += 0x7FFFu + ((u >> 16) & 1u);
    return (u16)(u >> 16);
}
__device__ __forceinline__ float bf16tof(u16 h) {
    return __uint_as_float(((unsigned int)h) << 16);
}

// async global->LDS, 16B per lane. LDS dest = wave-uniform base + lane*16.
__device__ __forceinline__ void gload16(const void* g, void* l) {
    __builtin_amdgcn_global_load_lds(
        (const __attribute__((address_space(1))) unsigned int*)g,
        (__attribute__((address_space(3))) unsigned int*)l, 16, 0, 0);
}

// ---------------------------------------------------------------------------
// Split-bf16 GEMM: C[M,N] = Ap[M,Kp] @ Wp[N,Kp]^T, fp32 accumulate.
// Ap rows = [hi|hi|lo], Wp rows = [hi|lo|hi]  => fp32-accurate product.
// 128x128 tile, BK=32, 256 thr = 4 waves (2x2 quadrants of 64x64),
// each wave: 4x4 grid of mfma_f32_16x16x32_bf16.
// Requires: M % 128 == 0, Kp % 32 == 0. N ragged (clamped loads, guarded st).
// ---------------------------------------------------------------------------
__global__ __launch_bounds__(256) void gemm_bf16s(
    const u16* __restrict__ Ap, const u16* __restrict__ Wp,
    float* __restrict__ C, int N, int Kp)
{
    __shared__ __align__(16) u16 As[128 * 32];
    __shared__ __align__(16) u16 Bs[128 * 32];

    const int t = threadIdx.x;
    const int lane = t & 63, w = t >> 6;
    const int col0 = blockIdx.x * 128;
    const long row0 = (long)blockIdx.y * 128;
    const int wm = w >> 1, wn = w & 1;

    float4v acc[4][4];
#pragma unroll
    for (int i = 0; i < 4; ++i)
#pragma unroll
        for (int j = 0; j < 4; ++j)
#pragma unroll
            for (int r = 0; r < 4; ++r) acc[i][j][r] = 0.f;

    // staging: wave w covers rows [w*32, w*32+32); instr p covers 16 rows.
    // lane -> row (lane>>2), k-offset (lane&3)*8 elems; LDS flat = lane*8 elems.
    const int srow = lane >> 2;
    const int skof = (lane & 3) * 8;

    const u16* aG0 = Ap + (row0 + w * 32 + srow) * (long)Kp + skof;
    const u16* aG1 = aG0 + 16 * (long)Kp;
    int bn0 = col0 + w * 32 + srow;      if (bn0 > N - 1) bn0 = N - 1;
    int bn1 = col0 + w * 32 + 16 + srow; if (bn1 > N - 1) bn1 = N - 1;
    const u16* bG0 = Wp + (long)bn0 * Kp + skof;
    const u16* bG1 = Wp + (long)bn1 * Kp + skof;

    u16* aL0 = &As[w * 1024];
    u16* aL1 = &As[w * 1024 + 512];
    u16* bL0 = &Bs[w * 1024];
    u16* bL1 = &Bs[w * 1024 + 512];

    // fragment read offset: row (lane&15) of the 16-row tile, k-quad (lane>>4)*8
    const int foff = (lane & 15) * 32 + (lane >> 4) * 8;
    const u16* aF = &As[wm * 64 * 32 + foff];
    const u16* bF = &Bs[wn * 64 * 32 + foff];

    for (int kt = 0; kt < Kp; kt += 32) {
        gload16(aG0 + kt, aL0);
        gload16(aG1 + kt, aL1);
        gload16(bG0 + kt, bL0);
        gload16(bG1 + kt, bL1);
        __syncthreads();   // drains vmcnt -> LDS slab visible to all waves

        short8v a[4], b[4];
#pragma unroll
        for (int i = 0; i < 4; ++i) a[i] = *(const short8v*)(aF + i * 512);
#pragma unroll
        for (int j = 0; j < 4; ++j) b[j] = *(const short8v*)(bF + j * 512);
#pragma unroll
        for (int i = 0; i < 4; ++i)
#pragma unroll
            for (int j = 0; j < 4; ++j)
                acc[i][j] = __builtin_amdgcn_mfma_f32_16x16x32_bf16(
                    a[i], b[j], acc[i][j], 0, 0, 0);
        __syncthreads();   // all reads done before next slab overwrite
    }

    // C/D layout: col = lane&15, row = (lane>>4)*4 + reg  [m89/m91 verified]
    const int cn = lane & 15, cq = lane >> 4;
#pragma unroll
    for (int i = 0; i < 4; ++i) {
        const long r0 = row0 + wm * 64 + i * 16 + cq * 4;
#pragma unroll
        for (int j = 0; j < 4; ++j) {
            const int col = col0 + wn * 64 + j * 16 + cn;
            if (col < N) {
#pragma unroll
                for (int r = 0; r < 4; ++r)
                    C[(r0 + r) * (long)N + col] = acc[i][j][r];
            }
        }
    }
}

// ---------------------------------------------------------------------------
// Pack fp32 (M x K, row stride rs) -> bf16 split (M x 3K).
// wmode 0 (A operand): [hi|hi|lo].  wmode 1 (W operand): [hi|lo|hi].
// ---------------------------------------------------------------------------
__global__ __launch_bounds__(256) void pack_split(
    const float* __restrict__ src, u16* __restrict__ dst,
    int M, int K, long rs, int wmode)
{
    const long idx = (long)blockIdx.x * 256 + threadIdx.x;
    const int k4cnt = K >> 2;
    if (idx >= (long)M * k4cnt) return;
    const int m = (int)(idx / k4cnt);
    const int k = (int)(idx % k4cnt) << 2;
    const float4 v = *(const float4*)(src + (long)m * rs + k);
    u16 h0 = bf16rn(v.x), h1 = bf16rn(v.y), h2 = bf16rn(v.z), h3 = bf16rn(v.w);
    u16 l0 = bf16rn(v.x - bf16tof(h0)), l1 = bf16rn(v.y - bf16tof(h1));
    u16 l2 = bf16rn(v.z - bf16tof(h2)), l3 = bf16rn(v.w - bf16tof(h3));
    ushort4 hv = make_ushort4(h0, h1, h2, h3);
    ushort4 lv = make_ushort4(l0, l1, l2, l3);
    u16* drow = dst + (long)m * (3 * K);
    *(ushort4*)(drow + k) = hv;
    *(ushort4*)(drow + K + k) = wmode ? lv : hv;
    *(ushort4*)(drow + 2 * K + k) = wmode ? hv : lv;
}

// ---------------------------------------------------------------------------
// Row LayerNorm (+ optional SiLU), in place. One block per row, 256 threads.
// ---------------------------------------------------------------------------
__global__ __launch_bounds__(256) void ln_rows(
    float* __restrict__ data, const float* __restrict__ g,
    const float* __restrict__ b, int ncols, int do_silu)
{
    const int row = blockIdx.x;
    const int t = threadIdx.x;
    float* drow = data + (long)row * ncols;

    float sum = 0.f, sumsq = 0.f;
    for (int c = t; c < ncols; c += 256) {
        float x = drow[c];
        sum += x; sumsq += x * x;
    }
#pragma unroll
    for (int off = 32; off; off >>= 1) {
        sum   += __shfl_xor(sum, off);
        sumsq += __shfl_xor(sumsq, off);
    }
    __shared__ float red[2][4];
    const int lane = t & 63, w = t >> 6;
    if (lane == 0) { red[0][w] = sum; red[1][w] = sumsq; }
    __syncthreads();
    sum   = red[0][0] + red[0][1] + red[0][2] + red[0][3];
    sumsq = red[1][0] + red[1][1] + red[1][2] + red[1][3];

    const float inv = 1.f / (float)ncols;
    const float mu  = sum * inv;
    const float var = sumsq * inv - mu * mu;
    const float r   = rsqrtf(var + 1e-5f);
    for (int c = t; c < ncols; c += 256) {
        float y = (drow[c] - mu) * r * g[c] + b[c];
        if (do_silu) y = y / (1.f + expf(-y));
        drow[c] = y;
    }
}

// ---------------------------------------------------------------------------
// Fused attention.
// R1 post-mortem: __launch_bounds__(256,4) capped VGPR at 128, allocator
// squeezed to 64 and spilled the unrolled qa/ka/acc + pa/va/o working sets
// to scratch (+1.7 GB HBM traffic/dispatch, dur 490->685). True live set is
// ~100 VGPRs.
// R2: __launch_bounds__(256,3) -> cap 170 (no spill), LDS 35.8 KB (2 slabs)
// -> 3 blocks/CU = 12 waves/CU, vs R0's 2 blocks/8 waves.
//  - V is streamed into the dead ks slab DURING the softmax loop.
//  - edge dot products vectorized (ds_read_b128).
// ---------------------------------------------------------------------------
__global__ __launch_bounds__(256, 3) void attn_fused(
    const float* __restrict__ qkv,   // (Bc*65, 2304)
    const float* __restrict__ bias,  // (Bc*12, 4225)
    const float* __restrict__ qn_g, const float* __restrict__ qn_b,
    const float* __restrict__ kn_g, const float* __restrict__ kn_b,
    float* __restrict__ attn_out)    // (Bc*65, 768)
{
    __shared__ __align__(16) float qs[NT][68];   // later aliased as P
    __shared__ __align__(16) float ks[NT][68];   // later aliased as V

    const int bh = blockIdx.x;
    const int b = bh / 12, h = bh % 12;
    const int t = threadIdx.x, lane = t & 63, w = t >> 6;
    const float scale = 0.125f;      // 64^-0.5

    const float qg = qn_g[lane], qb = qn_b[lane];
    const float kg = kn_g[lane], kb = kn_b[lane];
    const float* base = qkv + (long)(b * NT) * 2304 + h * 64;

    for (int n = w; n < NT; n += 4) {
        const float* row = base + (long)n * 2304;
        float qv = row[lane];
        float kv = row[768 + lane];

        float s = qv;
#pragma unroll
        for (int off = 32; off; off >>= 1) s += __shfl_xor(s, off);
        float mu = s * (1.f / 64.f);
        float dq = qv - mu;
        float s2 = dq * dq;
#pragma unroll
        for (int off = 32; off; off >>= 1) s2 += __shfl_xor(s2, off);
        qs[n][lane] = (dq * rsqrtf(s2 * (1.f / 64.f) + 1e-5f) * qg + qb) * scale;

        s = kv;
#pragma unroll
        for (int off = 32; off; off >>= 1) s += __shfl_xor(s, off);
        mu = s * (1.f / 64.f);
        float dk = kv - mu;
        s2 = dk * dk;
#pragma unroll
        for (int off = 32; off; off >>= 1) s2 += __shfl_xor(s2, off);
        ks[n][lane] = dk * rsqrtf(s2 * (1.f / 64.f) + 1e-5f) * kg + kb;
    }
    __syncthreads();

    const int tx = t & 15, ty = t >> 4;
    const int n0 = ty * 4, m0 = tx * 4;
    const float* brow = bias + (long)bh * 4225;

    float acc[4][4];
#pragma unroll
    for (int i = 0; i < 4; ++i)
#pragma unroll
        for (int j = 0; j < 4; ++j) acc[i][j] = 0.f;

    for (int d = 0; d < 64; d += 4) {
        float qa[4][4], ka[4][4];
#pragma unroll
        for (int i = 0; i < 4; ++i) {
            float4 tmp = *(const float4*)&qs[n0 + i][d];
            qa[i][0] = tmp.x; qa[i][1] = tmp.y; qa[i][2] = tmp.z; qa[i][3] = tmp.w;
        }
#pragma unroll
        for (int j = 0; j < 4; ++j) {
            float4 tmp = *(const float4*)&ks[m0 + j][d];
            ka[j][0] = tmp.x; ka[j][1] = tmp.y; ka[j][2] = tmp.z; ka[j][3] = tmp.w;
        }
#pragma unroll
        for (int i = 0; i < 4; ++i)
#pragma unroll
            for (int j = 0; j < 4; ++j)
#pragma unroll
                for (int k = 0; k < 4; ++k)
                    acc[i][j] = fmaf(qa[i][k], ka[j][k], acc[i][j]);
    }
#pragma unroll
    for (int i = 0; i < 4; ++i)
#pragma unroll
        for (int j = 0; j < 4; ++j)
            acc[i][j] += brow[(n0 + i) * 65 + (m0 + j)];

    float eacc = 0.f;
    int en = 0, em = 0;
    if (t < 129) {
        en = (t < 65) ? 64 : (t - 65);
        em = (t < 65) ? t  : 64;
#pragma unroll
        for (int d = 0; d < 64; d += 4) {
            float4 qa4 = *(const float4*)&qs[en][d];
            float4 ka4 = *(const float4*)&ks[em][d];
            eacc += qa4.x * ka4.x + qa4.y * ka4.y + qa4.z * ka4.z + qa4.w * ka4.w;
        }
        eacc += brow[en * 65 + em];
    }
    __syncthreads();

    float (*ps)[68] = qs;
    float (*vsd)[68] = ks;           // ks is dead after this point: reuse as V
#pragma unroll
    for (int i = 0; i < 4; ++i)
#pragma unroll
        for (int j = 0; j < 4; ++j)
            ps[n0 + i][m0 + j] = acc[i][j];
    if (t < 129) ps[en][em] = eacc;
    __syncthreads();

    // softmax rows + stream V into the dead ks slab (load hides under shuffles)
    for (int n = w; n < NT; n += 4) {
        float vv = base[(long)n * 2304 + 1536 + lane];
        float v0 = ps[n][lane];
        float v1 = (lane == 0) ? ps[n][64] : -1e30f;
        float mx = fmaxf(v0, v1);
#pragma unroll
        for (int off = 32; off; off >>= 1) mx = fmaxf(mx, __shfl_xor(mx, off));
        float e0 = __expf(v0 - mx);
        float e1 = (lane == 0) ? __expf(v1 - mx) : 0.f;
        float sm = e0 + e1;
#pragma unroll
        for (int off = 32; off; off >>= 1) sm += __shfl_xor(sm, off);
        float inv = 1.f / sm;
        ps[n][lane] = e0 * inv;
        if (lane == 0) ps[n][64] = e1 * inv;
        vsd[n][lane] = vv;
    }
    __syncthreads();

    const int d0 = tx * 4;
    float o[4][4];
#pragma unroll
    for (int i = 0; i < 4; ++i)
#pragma unroll
        for (int j = 0; j < 4; ++j) o[i][j] = 0.f;

    for (int m = 0; m < 64; m += 4) {
        float pa[4][4], va[4][4];
#pragma unroll
        for (int i = 0; i < 4; ++i) {
            float4 tmp = *(const float4*)&ps[n0 + i][m];
            pa[i][0] = tmp.x; pa[i][1] = tmp.y; pa[i][2] = tmp.z; pa[i][3] = tmp.w;
        }
#pragma unroll
        for (int jj = 0; jj < 4; ++jj) {
            float4 tmp = *(const float4*)&vsd[m + jj][d0];
            va[jj][0] = tmp.x; va[jj][1] = tmp.y; va[jj][2] = tmp.z; va[jj][3] = tmp.w;
        }
#pragma unroll
        for (int i = 0; i < 4; ++i)
#pragma unroll
            for (int k = 0; k < 4; ++k)
#pragma unroll
                for (int j = 0; j < 4; ++j)
                    o[i][j] = fmaf(pa[i][k], va[k][j], o[i][j]);
    }
#pragma unroll
    for (int i = 0; i < 4; ++i) {
        float p64 = ps[n0 + i][64];
#pragma unroll
        for (int j = 0; j < 4; ++j)
            o[i][j] = fmaf(p64, vsd[64][d0 + j], o[i][j]);
    }

    const long outbase = (long)(b * NT) * 768 + h * 64;
#pragma unroll
    for (int i = 0; i < 4; ++i)
        *(float4*)&attn_out[outbase + (long)(n0 + i) * 768 + d0] =
            make_float4(o[i][0], o[i][1], o[i][2], o[i][3]);

    if (t < 16) {
        const int dd = t * 4;
        float oo0 = 0.f, oo1 = 0.f, oo2 = 0.f, oo3 = 0.f;
        for (int m = 0; m < NT; ++m) {
            float p = ps[64][m];
            oo0 = fmaf(p, vsd[m][dd + 0], oo0);
            oo1 = fmaf(p, vsd[m][dd + 1], oo1);
            oo2 = fmaf(p, vsd[m][dd + 2], oo2);
            oo3 = fmaf(p, vsd[m][dd + 3], oo3);
        }
        *(float4*)&attn_out[outbase + 64L * 768 + dd] = make_float4(oo0, oo1, oo2, oo3);
    }
}

// ---------------------------------------------------------------------------
extern "C" void kernel_launch(void* const* d_in, const int* in_sizes, int n_in,
                              void* d_out, int out_size, void* d_ws, size_t ws_size,
                              hipStream_t stream)
{
    const float* x         = (const float*)d_in[0];
    const float* qkv_w     = (const float*)d_in[1];
    const float* proj_w    = (const float*)d_in[2];
    const float* qn_g      = (const float*)d_in[3];
    const float* qn_b      = (const float*)d_in[4];
    const float* kn_g      = (const float*)d_in[5];
    const float* kn_b      = (const float*)d_in[6];
    const float* sg_w1     = (const float*)d_in[7];
    const float* sg_ln1_g  = (const float*)d_in[8];
    const float* sg_ln1_b  = (const float*)d_in[9];
    const float* sg_w2     = (const float*)d_in[10];
    const float* sg_ln2_g  = (const float*)d_in[11];
    const float* sg_ln2_b  = (const float*)d_in[12];
    const float* sg_bias_w = (const float*)d_in[13];
    float* out = (float*)d_out;

    // Bc=256, 4 chunks. Total workspace = 388 MB (< 527 MB proven available).
    const int Bc = 256, nchunk = 4;
    const long Mq = (long)Bc * NT;          // 16640 rows (=130*128)

    float* ws     = (float*)d_ws;
    float* qkv_c  = ws;                     // 256*65*2304 = 38,338,560 f
    float* bias_c = qkv_c  + 38338560L;     // 256*12*4225 = 12,979,200 f
    float* aout_c = bias_c + 12979200L;     // 256*65*768  = 12,779,520 f
    float* lat1   = aout_c + 12779520L;     // 1024*512
    float* lat2   = lat1   + 524288L;       // 1024*3072
    u16*   P1     = (u16*)(lat2 + 3145728L);// 16640*2304 u16 (x / aout packed)
    u16*   clsp   = P1     + 38338560L;     // 1024*2304
    u16*   lat1p  = clsp   + 2359296L;      // 1024*1536
    u16*   lat2p  = lat1p  + 1572864L;      // 12288*768
    u16*   qkvwp  = lat2p  + 9437184L;      // 2304*2304
    u16*   projwp = qkvwp  + 5308416L;      // 768*2304
    u16*   sgw1p  = projwp + 1769472L;      // 512*2304
    u16*   sgw2p  = sgw1p  + 1179648L;      // 3072*1536
    u16*   sgbwp  = sgw2p  + 4718592L;      // 4225*768

    // ---- pack weights (wmode=1: [hi|lo|hi]) ----
    pack_split<<<(2304 * 192 + 255) / 256, 256, 0, stream>>>(qkv_w, qkvwp, 2304, 768, 768, 1);
    pack_split<<<( 768 * 192 + 255) / 256, 256, 0, stream>>>(proj_w, projwp, 768, 768, 768, 1);
    pack_split<<<( 512 * 192 + 255) / 256, 256, 0, stream>>>(sg_w1, sgw1p, 512, 768, 768, 1);
    pack_split<<<(3072 * 128 + 255) / 256, 256, 0, stream>>>(sg_w2, sgw2p, 3072, 512, 512, 1);
    pack_split<<<(4225 *  64 + 255) / 256, 256, 0, stream>>>(sg_bias_w, sgbwp, 4225, 256, 256, 1);

    // ---- bias MLP (whole batch) ----
    pack_split<<<(1024 * 192 + 255) / 256, 256, 0, stream>>>(x, clsp, 1024, 768, (long)NT * 768, 0);
    gemm_bf16s<<<dim3(512 / 128, 1024 / 128), 256, 0, stream>>>(clsp, sgw1p, lat1, 512, 2304);
    ln_rows<<<1024, 256, 0, stream>>>(lat1, sg_ln1_g, sg_ln1_b, 512, 1);
    pack_split<<<(1024 * 128 + 255) / 256, 256, 0, stream>>>(lat1, lat1p, 1024, 512, 512, 0);
    gemm_bf16s<<<dim3(3072 / 128, 1024 / 128), 256, 0, stream>>>(lat1p, sgw2p, lat2, 3072, 1536);
    ln_rows<<<1024, 256, 0, stream>>>(lat2, sg_ln2_g, sg_ln2_b, 3072, 0);
    pack_split<<<(12288 * 64 + 255) / 256, 256, 0, stream>>>(lat2, lat2p, 12288, 256, 256, 0);

    // ---- per-chunk pipeline ----
    for (int c = 0; c < nchunk; ++c) {
        const float* xc = x + (long)c * Mq * 768;

        // pack x chunk -> P1 (16640 x 2304)
        pack_split<<<(int)((Mq * 192 + 255) / 256), 256, 0, stream>>>(xc, P1, (int)Mq, 768, 768, 0);
        // qkv_c = xc @ qkv_w^T    (16640 x 2304, Kp=2304)
        gemm_bf16s<<<dim3(2304 / 128, (int)(Mq / 128)), 256, 0, stream>>>(P1, qkvwp, qkv_c, 2304, 2304);
        // bias_c = lat2p chunk @ sg_bias_w^T   (3072 x 4225, Kp=768)
        gemm_bf16s<<<dim3((4225 + 127) / 128, 3072 / 128), 256, 0, stream>>>(
            lat2p + (long)c * 3072 * 768, sgbwp, bias_c, 4225, 768);
        // fused attention -> aout_c
        attn_fused<<<Bc * 12, 256, 0, stream>>>(qkv_c, bias_c, qn_g, qn_b, kn_g, kn_b, aout_c);
        // pack aout -> P1 (16640 x 2304)
        pack_split<<<(int)((Mq * 192 + 255) / 256), 256, 0, stream>>>(aout_c, P1, (int)Mq, 768, 768, 0);
        // out chunk = aout @ proj_w^T   (16640 x 768, Kp=2304)
        gemm_bf16s<<<dim3(768 / 128, (int)(Mq / 128)), 256, 0, stream>>>(
            P1, projwp, out + (long)c * Mq * 768, 768, 2304);
    }
}

// Round 3
// 4552.914 us; speedup vs baseline: 1.1237x; 1.1237x over previous
//
#include <hip/hip_runtime.h>
#include <math.h>

// Problem constants (B=1024, N_TOK=65, C=768, H=12, D=64, L=256)
#define NT 65

typedef unsigned short u16;
typedef __attribute__((ext_vector_type(8))) short short8v;
typedef __attribute__((ext_vector_type(4))) float float4v;

__device__ __forceinline__ u16 bf16rn(float f) {
    unsigned int u = __float_as_uint(f);
    u += 0x7FFFu + ((u >> 16) & 1u);
    return (u16)(u >> 16);
}
__device__ __forceinline__ float bf16tof(u16 h) {
    return __uint_as_float(((unsigned int)h) << 16);
}

// async global->LDS, 16B per lane. LDS dest = wave-uniform base + lane*16.
__device__ __forceinline__ void gload16(const void* g, void* l) {
    __builtin_amdgcn_global_load_lds(
        (const __attribute__((address_space(1))) unsigned int*)g,
        (__attribute__((address_space(3))) unsigned int*)l, 16, 0, 0);
}

// ---------------------------------------------------------------------------
// Split-bf16 GEMM: C[M,N] = Ap[M,Kp] @ Wp[N,Kp]^T, fp32 accumulate.
// Ap rows = [hi|hi|lo], Wp rows = [hi|lo|hi]  => fp32-accurate product.
// 128x128 tile, BK=32, 256 thr = 4 waves (2x2 quadrants of 64x64),
// each wave: 4x4 grid of mfma_f32_16x16x32_bf16.
// Requires: M % 128 == 0, Kp % 32 == 0. N ragged (clamped loads, guarded st).
// R3: XCD-aware bijective block swizzle (T1/m204) -- each of the 8 XCDs gets
// a contiguous chunk of tile space, so tiles sharing an A-row panel hit the
// same per-XCD L2.
// ---------------------------------------------------------------------------
__global__ __launch_bounds__(256) void gemm_bf16s(
    const u16* __restrict__ Ap, const u16* __restrict__ Wp,
    float* __restrict__ C, int N, int Kp)
{
    __shared__ __align__(16) u16 As[128 * 32];
    __shared__ __align__(16) u16 Bs[128 * 32];

    const int t = threadIdx.x;
    const int lane = t & 63, w = t >> 6;

    // --- XCD swizzle (bijective for any nwg) ---
    const int nbx = gridDim.x;
    const int nwg = nbx * gridDim.y;
    const int o   = blockIdx.y * nbx + blockIdx.x;     // dispatch-linear id
    const int q8  = nwg >> 3, r8 = nwg & 7;
    const int xcd = o & 7, sl = o >> 3;
    const int logical = (xcd < r8 ? xcd * (q8 + 1)
                                  : r8 * (q8 + 1) + (xcd - r8) * q8) + sl;
    const int bx = logical % nbx, by = logical / nbx;

    const int col0 = bx * 128;
    const long row0 = (long)by * 128;
    const int wm = w >> 1, wn = w & 1;

    float4v acc[4][4];
#pragma unroll
    for (int i = 0; i < 4; ++i)
#pragma unroll
        for (int j = 0; j < 4; ++j)
#pragma unroll
            for (int r = 0; r < 4; ++r) acc[i][j][r] = 0.f;

    // staging: wave w covers rows [w*32, w*32+32); instr p covers 16 rows.
    // lane -> row (lane>>2), k-offset (lane&3)*8 elems; LDS flat = lane*8 elems.
    const int srow = lane >> 2;
    const int skof = (lane & 3) * 8;

    const u16* aG0 = Ap + (row0 + w * 32 + srow) * (long)Kp + skof;
    const u16* aG1 = aG0 + 16 * (long)Kp;
    int bn0 = col0 + w * 32 + srow;      if (bn0 > N - 1) bn0 = N - 1;
    int bn1 = col0 + w * 32 + 16 + srow; if (bn1 > N - 1) bn1 = N - 1;
    const u16* bG0 = Wp + (long)bn0 * Kp + skof;
    const u16* bG1 = Wp + (long)bn1 * Kp + skof;

    u16* aL0 = &As[w * 1024];
    u16* aL1 = &As[w * 1024 + 512];
    u16* bL0 = &Bs[w * 1024];
    u16* bL1 = &Bs[w * 1024 + 512];

    // fragment read offset: row (lane&15) of the 16-row tile, k-quad (lane>>4)*8
    const int foff = (lane & 15) * 32 + (lane >> 4) * 8;
    const u16* aF = &As[wm * 64 * 32 + foff];
    const u16* bF = &Bs[wn * 64 * 32 + foff];

    for (int kt = 0; kt < Kp; kt += 32) {
        gload16(aG0 + kt, aL0);
        gload16(aG1 + kt, aL1);
        gload16(bG0 + kt, bL0);
        gload16(bG1 + kt, bL1);
        __syncthreads();   // drains vmcnt -> LDS slab visible to all waves

        short8v a[4], b[4];
#pragma unroll
        for (int i = 0; i < 4; ++i) a[i] = *(const short8v*)(aF + i * 512);
#pragma unroll
        for (int j = 0; j < 4; ++j) b[j] = *(const short8v*)(bF + j * 512);
#pragma unroll
        for (int i = 0; i < 4; ++i)
#pragma unroll
            for (int j = 0; j < 4; ++j)
                acc[i][j] = __builtin_amdgcn_mfma_f32_16x16x32_bf16(
                    a[i], b[j], acc[i][j], 0, 0, 0);
        __syncthreads();   // all reads done before next slab overwrite
    }

    // C/D layout: col = lane&15, row = (lane>>4)*4 + reg  [m89/m91 verified]
    const int cn = lane & 15, cq = lane >> 4;
#pragma unroll
    for (int i = 0; i < 4; ++i) {
        const long r0 = row0 + wm * 64 + i * 16 + cq * 4;
#pragma unroll
        for (int j = 0; j < 4; ++j) {
            const int col = col0 + wn * 64 + j * 16 + cn;
            if (col < N) {
#pragma unroll
                for (int r = 0; r < 4; ++r)
                    C[(r0 + r) * (long)N + col] = acc[i][j][r];
            }
        }
    }
}

// ---------------------------------------------------------------------------
// Pack fp32 (M x K, row stride rs) -> bf16 split (M x 3K).
// wmode 0 (A operand): [hi|hi|lo].  wmode 1 (W operand): [hi|lo|hi].
// ---------------------------------------------------------------------------
__global__ __launch_bounds__(256) void pack_split(
    const float* __restrict__ src, u16* __restrict__ dst,
    int M, int K, long rs, int wmode)
{
    const long idx = (long)blockIdx.x * 256 + threadIdx.x;
    const int k4cnt = K >> 2;
    if (idx >= (long)M * k4cnt) return;
    const int m = (int)(idx / k4cnt);
    const int k = (int)(idx % k4cnt) << 2;
    const float4 v = *(const float4*)(src + (long)m * rs + k);
    u16 h0 = bf16rn(v.x), h1 = bf16rn(v.y), h2 = bf16rn(v.z), h3 = bf16rn(v.w);
    u16 l0 = bf16rn(v.x - bf16tof(h0)), l1 = bf16rn(v.y - bf16tof(h1));
    u16 l2 = bf16rn(v.z - bf16tof(h2)), l3 = bf16rn(v.w - bf16tof(h3));
    ushort4 hv = make_ushort4(h0, h1, h2, h3);
    ushort4 lv = make_ushort4(l0, l1, l2, l3);
    u16* drow = dst + (long)m * (3 * K);
    *(ushort4*)(drow + k) = hv;
    *(ushort4*)(drow + K + k) = wmode ? lv : hv;
    *(ushort4*)(drow + 2 * K + k) = wmode ? hv : lv;
}

// ---------------------------------------------------------------------------
// Row LayerNorm (+ optional SiLU), in place. One block per row, 256 threads.
// ---------------------------------------------------------------------------
__global__ __launch_bounds__(256) void ln_rows(
    float* __restrict__ data, const float* __restrict__ g,
    const float* __restrict__ b, int ncols, int do_silu)
{
    const int row = blockIdx.x;
    const int t = threadIdx.x;
    float* drow = data + (long)row * ncols;

    float sum = 0.f, sumsq = 0.f;
    for (int c = t; c < ncols; c += 256) {
        float x = drow[c];
        sum += x; sumsq += x * x;
    }
#pragma unroll
    for (int off = 32; off; off >>= 1) {
        sum   += __shfl_xor(sum, off);
        sumsq += __shfl_xor(sumsq, off);
    }
    __shared__ float red[2][4];
    const int lane = t & 63, w = t >> 6;
    if (lane == 0) { red[0][w] = sum; red[1][w] = sumsq; }
    __syncthreads();
    sum   = red[0][0] + red[0][1] + red[0][2] + red[0][3];
    sumsq = red[1][0] + red[1][1] + red[1][2] + red[1][3];

    const float inv = 1.f / (float)ncols;
    const float mu  = sum * inv;
    const float var = sumsq * inv - mu * mu;
    const float r   = rsqrtf(var + 1e-5f);
    for (int c = t; c < ncols; c += 256) {
        float y = (drow[c] - mu) * r * g[c] + b[c];
        if (do_silu) y = y / (1.f + expf(-y));
        drow[c] = y;
    }
}

// ---------------------------------------------------------------------------
// Fused attention.
// R1/R2 post-mortem: HIP's __launch_bounds__ 2nd arg is accounted in wave32
// units: (256,N) -> 2N waves/EU target -> VGPR budget 512/(2N).
//   (256,4) -> 64 regs (catastrophic spill), (256,3) -> 84 (spill).
// R3: (256,2) -> 4 waves/EU -> budget 128, fits the ~100-reg live set with
// no spill. LDS 35.8 KB (2 slabs) -> 4 blocks/CU; VGPR 128 -> 16 waves/CU
// -> 4 blocks/CU resident (50% occupancy), vs R0's 2 blocks / 8 waves.
//  - V is streamed into the dead ks slab DURING the softmax loop.
//  - edge dot products vectorized (ds_read_b128).
// Numerics identical to R0/R1/R2 (all passed, absmax 0.001953125).
// ---------------------------------------------------------------------------
__global__ __launch_bounds__(256, 2) void attn_fused(
    const float* __restrict__ qkv,   // (Bc*65, 2304)
    const float* __restrict__ bias,  // (Bc*12, 4225)
    const float* __restrict__ qn_g, const float* __restrict__ qn_b,
    const float* __restrict__ kn_g, const float* __restrict__ kn_b,
    float* __restrict__ attn_out)    // (Bc*65, 768)
{
    __shared__ __align__(16) float qs[NT][68];   // later aliased as P
    __shared__ __align__(16) float ks[NT][68];   // later aliased as V

    const int bh = blockIdx.x;
    const int b = bh / 12, h = bh % 12;
    const int t = threadIdx.x, lane = t & 63, w = t >> 6;
    const float scale = 0.125f;      // 64^-0.5

    const float qg = qn_g[lane], qb = qn_b[lane];
    const float kg = kn_g[lane], kb = kn_b[lane];
    const float* base = qkv + (long)(b * NT) * 2304 + h * 64;

    for (int n = w; n < NT; n += 4) {
        const float* row = base + (long)n * 2304;
        float qv = row[lane];
        float kv = row[768 + lane];

        float s = qv;
#pragma unroll
        for (int off = 32; off; off >>= 1) s += __shfl_xor(s, off);
        float mu = s * (1.f / 64.f);
        float dq = qv - mu;
        float s2 = dq * dq;
#pragma unroll
        for (int off = 32; off; off >>= 1) s2 += __shfl_xor(s2, off);
        qs[n][lane] = (dq * rsqrtf(s2 * (1.f / 64.f) + 1e-5f) * qg + qb) * scale;

        s = kv;
#pragma unroll
        for (int off = 32; off; off >>= 1) s += __shfl_xor(s, off);
        mu = s * (1.f / 64.f);
        float dk = kv - mu;
        s2 = dk * dk;
#pragma unroll
        for (int off = 32; off; off >>= 1) s2 += __shfl_xor(s2, off);
        ks[n][lane] = dk * rsqrtf(s2 * (1.f / 64.f) + 1e-5f) * kg + kb;
    }
    __syncthreads();

    const int tx = t & 15, ty = t >> 4;
    const int n0 = ty * 4, m0 = tx * 4;
    const float* brow = bias + (long)bh * 4225;

    float acc[4][4];
#pragma unroll
    for (int i = 0; i < 4; ++i)
#pragma unroll
        for (int j = 0; j < 4; ++j) acc[i][j] = 0.f;

    for (int d = 0; d < 64; d += 4) {
        float qa[4][4], ka[4][4];
#pragma unroll
        for (int i = 0; i < 4; ++i) {
            float4 tmp = *(const float4*)&qs[n0 + i][d];
            qa[i][0] = tmp.x; qa[i][1] = tmp.y; qa[i][2] = tmp.z; qa[i][3] = tmp.w;
        }
#pragma unroll
        for (int j = 0; j < 4; ++j) {
            float4 tmp = *(const float4*)&ks[m0 + j][d];
            ka[j][0] = tmp.x; ka[j][1] = tmp.y; ka[j][2] = tmp.z; ka[j][3] = tmp.w;
        }
#pragma unroll
        for (int i = 0; i < 4; ++i)
#pragma unroll
            for (int j = 0; j < 4; ++j)
#pragma unroll
                for (int k = 0; k < 4; ++k)
                    acc[i][j] = fmaf(qa[i][k], ka[j][k], acc[i][j]);
    }
#pragma unroll
    for (int i = 0; i < 4; ++i)
#pragma unroll
        for (int j = 0; j < 4; ++j)
            acc[i][j] += brow[(n0 + i) * 65 + (m0 + j)];

    float eacc = 0.f;
    int en = 0, em = 0;
    if (t < 129) {
        en = (t < 65) ? 64 : (t - 65);
        em = (t < 65) ? t  : 64;
#pragma unroll
        for (int d = 0; d < 64; d += 4) {
            float4 qa4 = *(const float4*)&qs[en][d];
            float4 ka4 = *(const float4*)&ks[em][d];
            eacc += qa4.x * ka4.x + qa4.y * ka4.y + qa4.z * ka4.z + qa4.w * ka4.w;
        }
        eacc += brow[en * 65 + em];
    }
    __syncthreads();

    float (*ps)[68] = qs;
    float (*vsd)[68] = ks;           // ks is dead after this point: reuse as V
#pragma unroll
    for (int i = 0; i < 4; ++i)
#pragma unroll
        for (int j = 0; j < 4; ++j)
            ps[n0 + i][m0 + j] = acc[i][j];
    if (t < 129) ps[en][em] = eacc;
    __syncthreads();

    // softmax rows + stream V into the dead ks slab (load hides under shuffles)
    for (int n = w; n < NT; n += 4) {
        float vv = base[(long)n * 2304 + 1536 + lane];
        float v0 = ps[n][lane];
        float v1 = (lane == 0) ? ps[n][64] : -1e30f;
        float mx = fmaxf(v0, v1);
#pragma unroll
        for (int off = 32; off; off >>= 1) mx = fmaxf(mx, __shfl_xor(mx, off));
        float e0 = __expf(v0 - mx);
        float e1 = (lane == 0) ? __expf(v1 - mx) : 0.f;
        float sm = e0 + e1;
#pragma unroll
        for (int off = 32; off; off >>= 1) sm += __shfl_xor(sm, off);
        float inv = 1.f / sm;
        ps[n][lane] = e0 * inv;
        if (lane == 0) ps[n][64] = e1 * inv;
        vsd[n][lane] = vv;
    }
    __syncthreads();

    const int d0 = tx * 4;
    float o[4][4];
#pragma unroll
    for (int i = 0; i < 4; ++i)
#pragma unroll
        for (int j = 0; j < 4; ++j) o[i][j] = 0.f;

    for (int m = 0; m < 64; m += 4) {
        float pa[4][4], va[4][4];
#pragma unroll
        for (int i = 0; i < 4; ++i) {
            float4 tmp = *(const float4*)&ps[n0 + i][m];
            pa[i][0] = tmp.x; pa[i][1] = tmp.y; pa[i][2] = tmp.z; pa[i][3] = tmp.w;
        }
#pragma unroll
        for (int jj = 0; jj < 4; ++jj) {
            float4 tmp = *(const float4*)&vsd[m + jj][d0];
            va[jj][0] = tmp.x; va[jj][1] = tmp.y; va[jj][2] = tmp.z; va[jj][3] = tmp.w;
        }
#pragma unroll
        for (int i = 0; i < 4; ++i)
#pragma unroll
            for (int k = 0; k < 4; ++k)
#pragma unroll
                for (int j = 0; j < 4; ++j)
                    o[i][j] = fmaf(pa[i][k], va[k][j], o[i][j]);
    }
#pragma unroll
    for (int i = 0; i < 4; ++i) {
        float p64 = ps[n0 + i][64];
#pragma unroll
        for (int j = 0; j < 4; ++j)
            o[i][j] = fmaf(p64, vsd[64][d0 + j], o[i][j]);
    }

    const long outbase = (long)(b * NT) * 768 + h * 64;
#pragma unroll
    for (int i = 0; i < 4; ++i)
        *(float4*)&attn_out[outbase + (long)(n0 + i) * 768 + d0] =
            make_float4(o[i][0], o[i][1], o[i][2], o[i][3]);

    if (t < 16) {
        const int dd = t * 4;
        float oo0 = 0.f, oo1 = 0.f, oo2 = 0.f, oo3 = 0.f;
        for (int m = 0; m < NT; ++m) {
            float p = ps[64][m];
            oo0 = fmaf(p, vsd[m][dd + 0], oo0);
            oo1 = fmaf(p, vsd[m][dd + 1], oo1);
            oo2 = fmaf(p, vsd[m][dd + 2], oo2);
            oo3 = fmaf(p, vsd[m][dd + 3], oo3);
        }
        *(float4*)&attn_out[outbase + 64L * 768 + dd] = make_float4(oo0, oo1, oo2, oo3);
    }
}

// ---------------------------------------------------------------------------
extern "C" void kernel_launch(void* const* d_in, const int* in_sizes, int n_in,
                              void* d_out, int out_size, void* d_ws, size_t ws_size,
                              hipStream_t stream)
{
    const float* x         = (const float*)d_in[0];
    const float* qkv_w     = (const float*)d_in[1];
    const float* proj_w    = (const float*)d_in[2];
    const float* qn_g      = (const float*)d_in[3];
    const float* qn_b      = (const float*)d_in[4];
    const float* kn_g      = (const float*)d_in[5];
    const float* kn_b      = (const float*)d_in[6];
    const float* sg_w1     = (const float*)d_in[7];
    const float* sg_ln1_g  = (const float*)d_in[8];
    const float* sg_ln1_b  = (const float*)d_in[9];
    const float* sg_w2     = (const float*)d_in[10];
    const float* sg_ln2_g  = (const float*)d_in[11];
    const float* sg_ln2_b  = (const float*)d_in[12];
    const float* sg_bias_w = (const float*)d_in[13];
    float* out = (float*)d_out;

    // Bc=256, 4 chunks. Total workspace = 388 MB (< 527 MB proven available).
    const int Bc = 256, nchunk = 4;
    const long Mq = (long)Bc * NT;          // 16640 rows (=130*128)

    float* ws     = (float*)d_ws;
    float* qkv_c  = ws;                     // 256*65*2304 = 38,338,560 f
    float* bias_c = qkv_c  + 38338560L;     // 256*12*4225 = 12,979,200 f
    float* aout_c = bias_c + 12979200L;     // 256*65*768  = 12,779,520 f
    float* lat1   = aout_c + 12779520L;     // 1024*512
    float* lat2   = lat1   + 524288L;       // 1024*3072
    u16*   P1     = (u16*)(lat2 + 3145728L);// 16640*2304 u16 (x / aout packed)
    u16*   clsp   = P1     + 38338560L;     // 1024*2304
    u16*   lat1p  = clsp   + 2359296L;      // 1024*1536
    u16*   lat2p  = lat1p  + 1572864L;      // 12288*768
    u16*   qkvwp  = lat2p  + 9437184L;      // 2304*2304
    u16*   projwp = qkvwp  + 5308416L;      // 768*2304
    u16*   sgw1p  = projwp + 1769472L;      // 512*2304
    u16*   sgw2p  = sgw1p  + 1179648L;      // 3072*1536
    u16*   sgbwp  = sgw2p  + 4718592L;      // 4225*768

    // ---- pack weights (wmode=1: [hi|lo|hi]) ----
    pack_split<<<(2304 * 192 + 255) / 256, 256, 0, stream>>>(qkv_w, qkvwp, 2304, 768, 768, 1);
    pack_split<<<( 768 * 192 + 255) / 256, 256, 0, stream>>>(proj_w, projwp, 768, 768, 768, 1);
    pack_split<<<( 512 * 192 + 255) / 256, 256, 0, stream>>>(sg_w1, sgw1p, 512, 768, 768, 1);
    pack_split<<<(3072 * 128 + 255) / 256, 256, 0, stream>>>(sg_w2, sgw2p, 3072, 512, 512, 1);
    pack_split<<<(4225 *  64 + 255) / 256, 256, 0, stream>>>(sg_bias_w, sgbwp, 4225, 256, 256, 1);

    // ---- bias MLP (whole batch) ----
    pack_split<<<(1024 * 192 + 255) / 256, 256, 0, stream>>>(x, clsp, 1024, 768, (long)NT * 768, 0);
    gemm_bf16s<<<dim3(512 / 128, 1024 / 128), 256, 0, stream>>>(clsp, sgw1p, lat1, 512, 2304);
    ln_rows<<<1024, 256, 0, stream>>>(lat1, sg_ln1_g, sg_ln1_b, 512, 1);
    pack_split<<<(1024 * 128 + 255) / 256, 256, 0, stream>>>(lat1, lat1p, 1024, 512, 512, 0);
    gemm_bf16s<<<dim3(3072 / 128, 1024 / 128), 256, 0, stream>>>(lat1p, sgw2p, lat2, 3072, 1536);
    ln_rows<<<1024, 256, 0, stream>>>(lat2, sg_ln2_g, sg_ln2_b, 3072, 0);
    pack_split<<<(12288 * 64 + 255) / 256, 256, 0, stream>>>(lat2, lat2p, 12288, 256, 256, 0);

    // ---- per-chunk pipeline ----
    for (int c = 0; c < nchunk; ++c) {
        const float* xc = x + (long)c * Mq * 768;

        // pack x chunk -> P1 (16640 x 2304)
        pack_split<<<(int)((Mq * 192 + 255) / 256), 256, 0, stream>>>(xc, P1, (int)Mq, 768, 768, 0);
        // qkv_c = xc @ qkv_w^T    (16640 x 2304, Kp=2304)
        gemm_bf16s<<<dim3(2304 / 128, (int)(Mq / 128)), 256, 0, stream>>>(P1, qkvwp, qkv_c, 2304, 2304);
        // bias_c = lat2p chunk @ sg_bias_w^T   (3072 x 4225, Kp=768)
        gemm_bf16s<<<dim3((4225 + 127) / 128, 3072 / 128), 256, 0, stream>>>(
            lat2p + (long)c * 3072 * 768, sgbwp, bias_c, 4225, 768);
        // fused attention -> aout_c
        attn_fused<<<Bc * 12, 256, 0, stream>>>(qkv_c, bias_c, qn_g, qn_b, kn_g, kn_b, aout_c);
        // pack aout -> P1 (16640 x 2304)
        pack_split<<<(int)((Mq * 192 + 255) / 256), 256, 0, stream>>>(aout_c, P1, (int)Mq, 768, 768, 0);
        // out chunk = aout @ proj_w^T   (16640 x 768, Kp=2304)
        gemm_bf16s<<<dim3(768 / 128, (int)(Mq / 128)), 256, 0, stream>>>(
            P1, projwp, out + (long)c * Mq * 768, 768, 2304);
    }
}

// Round 4
// 2935.105 us; speedup vs baseline: 1.7431x; 1.5512x over previous
//
#include <hip/hip_runtime.h>
#include <math.h>

// Problem constants (B=1024, N_TOK=65, C=768, H=12, D=64, L=256)
#define NT 65

typedef unsigned short u16;
typedef __attribute__((ext_vector_type(8))) short short8v;
typedef __attribute__((ext_vector_type(4))) float float4v;

__device__ __forceinline__ u16 bf16rn(float f) {
    unsigned int u = __float_as_uint(f);
    u += 0x7FFFu + ((u >> 16) & 1u);
    return (u16)(u >> 16);
}
__device__ __forceinline__ float bf16tof(u16 h) {
    return __uint_as_float(((unsigned int)h) << 16);
}

// async global->LDS, 16B per lane. LDS dest = wave-uniform base + lane*16.
__device__ __forceinline__ void gload16(const void* g, void* l) {
    __builtin_amdgcn_global_load_lds(
        (const __attribute__((address_space(1))) unsigned int*)g,
        (__attribute__((address_space(3))) unsigned int*)l, 16, 0, 0);
}

// ---------------------------------------------------------------------------
// Split-bf16 GEMM: C[M,N] = Ap[M,Kp] @ Wp[N,Kp]^T, fp32 accumulate.
// Ap rows = [hi|hi|lo], Wp rows = [hi|lo|hi]  => fp32-accurate product.
// 128x128 tile, BK=32, 256 thr = 4 waves (2x2 quadrants of 64x64),
// each wave: 4x4 grid of mfma_f32_16x16x32_bf16.
// Requires: M % 128 == 0, Kp % 32 == 0. N ragged (clamped loads, guarded st).
// XCD-aware bijective block swizzle (T1/m204).
// ---------------------------------------------------------------------------
__global__ __launch_bounds__(256) void gemm_bf16s(
    const u16* __restrict__ Ap, const u16* __restrict__ Wp,
    float* __restrict__ C, int N, int Kp)
{
    __shared__ __align__(16) u16 As[128 * 32];
    __shared__ __align__(16) u16 Bs[128 * 32];

    const int t = threadIdx.x;
    const int lane = t & 63, w = t >> 6;

    // --- XCD swizzle (bijective for any nwg) ---
    const int nbx = gridDim.x;
    const int nwg = nbx * gridDim.y;
    const int o   = blockIdx.y * nbx + blockIdx.x;     // dispatch-linear id
    const int q8  = nwg >> 3, r8 = nwg & 7;
    const int xcd = o & 7, sl = o >> 3;
    const int logical = (xcd < r8 ? xcd * (q8 + 1)
                                  : r8 * (q8 + 1) + (xcd - r8) * q8) + sl;
    const int bx = logical % nbx, by = logical / nbx;

    const int col0 = bx * 128;
    const long row0 = (long)by * 128;
    const int wm = w >> 1, wn = w & 1;

    float4v acc[4][4];
#pragma unroll
    for (int i = 0; i < 4; ++i)
#pragma unroll
        for (int j = 0; j < 4; ++j)
#pragma unroll
            for (int r = 0; r < 4; ++r) acc[i][j][r] = 0.f;

    // staging: wave w covers rows [w*32, w*32+32); instr p covers 16 rows.
    // lane -> row (lane>>2), k-offset (lane&3)*8 elems; LDS flat = lane*8 elems.
    const int srow = lane >> 2;
    const int skof = (lane & 3) * 8;

    const u16* aG0 = Ap + (row0 + w * 32 + srow) * (long)Kp + skof;
    const u16* aG1 = aG0 + 16 * (long)Kp;
    int bn0 = col0 + w * 32 + srow;      if (bn0 > N - 1) bn0 = N - 1;
    int bn1 = col0 + w * 32 + 16 + srow; if (bn1 > N - 1) bn1 = N - 1;
    const u16* bG0 = Wp + (long)bn0 * Kp + skof;
    const u16* bG1 = Wp + (long)bn1 * Kp + skof;

    u16* aL0 = &As[w * 1024];
    u16* aL1 = &As[w * 1024 + 512];
    u16* bL0 = &Bs[w * 1024];
    u16* bL1 = &Bs[w * 1024 + 512];

    // fragment read offset: row (lane&15) of the 16-row tile, k-quad (lane>>4)*8
    const int foff = (lane & 15) * 32 + (lane >> 4) * 8;
    const u16* aF = &As[wm * 64 * 32 + foff];
    const u16* bF = &Bs[wn * 64 * 32 + foff];

    for (int kt = 0; kt < Kp; kt += 32) {
        gload16(aG0 + kt, aL0);
        gload16(aG1 + kt, aL1);
        gload16(bG0 + kt, bL0);
        gload16(bG1 + kt, bL1);
        __syncthreads();   // drains vmcnt -> LDS slab visible to all waves

        short8v a[4], b[4];
#pragma unroll
        for (int i = 0; i < 4; ++i) a[i] = *(const short8v*)(aF + i * 512);
#pragma unroll
        for (int j = 0; j < 4; ++j) b[j] = *(const short8v*)(bF + j * 512);
#pragma unroll
        for (int i = 0; i < 4; ++i)
#pragma unroll
            for (int j = 0; j < 4; ++j)
                acc[i][j] = __builtin_amdgcn_mfma_f32_16x16x32_bf16(
                    a[i], b[j], acc[i][j], 0, 0, 0);
        __syncthreads();   // all reads done before next slab overwrite
    }

    // C/D layout: col = lane&15, row = (lane>>4)*4 + reg  [m89/m91 verified]
    const int cn = lane & 15, cq = lane >> 4;
#pragma unroll
    for (int i = 0; i < 4; ++i) {
        const long r0 = row0 + wm * 64 + i * 16 + cq * 4;
#pragma unroll
        for (int j = 0; j < 4; ++j) {
            const int col = col0 + wn * 64 + j * 16 + cn;
            if (col < N) {
#pragma unroll
                for (int r = 0; r < 4; ++r)
                    C[(r0 + r) * (long)N + col] = acc[i][j][r];
            }
        }
    }
}

// ---------------------------------------------------------------------------
// Pack fp32 (M x K, row stride rs) -> bf16 split (M x 3K).
// wmode 0 (A operand): [hi|hi|lo].  wmode 1 (W operand): [hi|lo|hi].
// ---------------------------------------------------------------------------
__global__ __launch_bounds__(256) void pack_split(
    const float* __restrict__ src, u16* __restrict__ dst,
    int M, int K, long rs, int wmode)
{
    const long idx = (long)blockIdx.x * 256 + threadIdx.x;
    const int k4cnt = K >> 2;
    if (idx >= (long)M * k4cnt) return;
    const int m = (int)(idx / k4cnt);
    const int k = (int)(idx % k4cnt) << 2;
    const float4 v = *(const float4*)(src + (long)m * rs + k);
    u16 h0 = bf16rn(v.x), h1 = bf16rn(v.y), h2 = bf16rn(v.z), h3 = bf16rn(v.w);
    u16 l0 = bf16rn(v.x - bf16tof(h0)), l1 = bf16rn(v.y - bf16tof(h1));
    u16 l2 = bf16rn(v.z - bf16tof(h2)), l3 = bf16rn(v.w - bf16tof(h3));
    ushort4 hv = make_ushort4(h0, h1, h2, h3);
    ushort4 lv = make_ushort4(l0, l1, l2, l3);
    u16* drow = dst + (long)m * (3 * K);
    *(ushort4*)(drow + k) = hv;
    *(ushort4*)(drow + K + k) = wmode ? lv : hv;
    *(ushort4*)(drow + 2 * K + k) = wmode ? hv : lv;
}

// ---------------------------------------------------------------------------
// Row LayerNorm (+ optional SiLU), in place. One block per row, 256 threads.
// ---------------------------------------------------------------------------
__global__ __launch_bounds__(256) void ln_rows(
    float* __restrict__ data, const float* __restrict__ g,
    const float* __restrict__ b, int ncols, int do_silu)
{
    const int row = blockIdx.x;
    const int t = threadIdx.x;
    float* drow = data + (long)row * ncols;

    float sum = 0.f, sumsq = 0.f;
    for (int c = t; c < ncols; c += 256) {
        float x = drow[c];
        sum += x; sumsq += x * x;
    }
#pragma unroll
    for (int off = 32; off; off >>= 1) {
        sum   += __shfl_xor(sum, off);
        sumsq += __shfl_xor(sumsq, off);
    }
    __shared__ float red[2][4];
    const int lane = t & 63, w = t >> 6;
    if (lane == 0) { red[0][w] = sum; red[1][w] = sumsq; }
    __syncthreads();
    sum   = red[0][0] + red[0][1] + red[0][2] + red[0][3];
    sumsq = red[1][0] + red[1][1] + red[1][2] + red[1][3];

    const float inv = 1.f / (float)ncols;
    const float mu  = sum * inv;
    const float var = sumsq * inv - mu * mu;
    const float r   = rsqrtf(var + 1e-5f);
    for (int c = t; c < ncols; c += 256) {
        float y = (drow[c] - mu) * r * g[c] + b[c];
        if (do_silu) y = y / (1.f + expf(-y));
        drow[c] = y;
    }
}

// ---------------------------------------------------------------------------
// Fused attention.
// R3 post-mortem: spill persisted at VGPR=128 because the compile-time-
// constant d-loop and m-loop (16 iters) were FULLY unrolled -- the scheduler
// hoists all 128 LDS operand loads, inflating liveness to ~256 regs.
// R4: (a) #pragma unroll 2 bounds the operand liveness to ~80-100 regs;
//     (b) amdgpu_waves_per_eu(3) -- NATIVE wave64 units (launch_bounds' 2nd
//         arg is doubled: (256,3)->84 regs, (256,4)->64 observed) -> VGPR
//         budget 168 -> 12 waves/CU = 3 blocks/CU, no spill expected.
// LDS 35.8 KB (2 slabs, V streamed into dead ks slab during softmax).
// Numerics identical to R0..R3 (all passed, absmax 0.001953125).
// ---------------------------------------------------------------------------
__global__ __launch_bounds__(256) __attribute__((amdgpu_waves_per_eu(3)))
void attn_fused(
    const float* __restrict__ qkv,   // (Bc*65, 2304)
    const float* __restrict__ bias,  // (Bc*12, 4225)
    const float* __restrict__ qn_g, const float* __restrict__ qn_b,
    const float* __restrict__ kn_g, const float* __restrict__ kn_b,
    float* __restrict__ attn_out)    // (Bc*65, 768)
{
    __shared__ __align__(16) float qs[NT][68];   // later aliased as P
    __shared__ __align__(16) float ks[NT][68];   // later aliased as V

    const int bh = blockIdx.x;
    const int b = bh / 12, h = bh % 12;
    const int t = threadIdx.x, lane = t & 63, w = t >> 6;
    const float scale = 0.125f;      // 64^-0.5

    const float qg = qn_g[lane], qb = qn_b[lane];
    const float kg = kn_g[lane], kb = kn_b[lane];
    const float* base = qkv + (long)(b * NT) * 2304 + h * 64;

    for (int n = w; n < NT; n += 4) {
        const float* row = base + (long)n * 2304;
        float qv = row[lane];
        float kv = row[768 + lane];

        float s = qv;
#pragma unroll
        for (int off = 32; off; off >>= 1) s += __shfl_xor(s, off);
        float mu = s * (1.f / 64.f);
        float dq = qv - mu;
        float s2 = dq * dq;
#pragma unroll
        for (int off = 32; off; off >>= 1) s2 += __shfl_xor(s2, off);
        qs[n][lane] = (dq * rsqrtf(s2 * (1.f / 64.f) + 1e-5f) * qg + qb) * scale;

        s = kv;
#pragma unroll
        for (int off = 32; off; off >>= 1) s += __shfl_xor(s, off);
        mu = s * (1.f / 64.f);
        float dk = kv - mu;
        s2 = dk * dk;
#pragma unroll
        for (int off = 32; off; off >>= 1) s2 += __shfl_xor(s2, off);
        ks[n][lane] = dk * rsqrtf(s2 * (1.f / 64.f) + 1e-5f) * kg + kb;
    }
    __syncthreads();

    const int tx = t & 15, ty = t >> 4;
    const int n0 = ty * 4, m0 = tx * 4;
    const float* brow = bias + (long)bh * 4225;

    float acc[4][4];
#pragma unroll
    for (int i = 0; i < 4; ++i)
#pragma unroll
        for (int j = 0; j < 4; ++j) acc[i][j] = 0.f;

#pragma unroll 2
    for (int d = 0; d < 64; d += 4) {
        float qa[4][4], ka[4][4];
#pragma unroll
        for (int i = 0; i < 4; ++i) {
            float4 tmp = *(const float4*)&qs[n0 + i][d];
            qa[i][0] = tmp.x; qa[i][1] = tmp.y; qa[i][2] = tmp.z; qa[i][3] = tmp.w;
        }
#pragma unroll
        for (int j = 0; j < 4; ++j) {
            float4 tmp = *(const float4*)&ks[m0 + j][d];
            ka[j][0] = tmp.x; ka[j][1] = tmp.y; ka[j][2] = tmp.z; ka[j][3] = tmp.w;
        }
#pragma unroll
        for (int i = 0; i < 4; ++i)
#pragma unroll
            for (int j = 0; j < 4; ++j)
#pragma unroll
                for (int k = 0; k < 4; ++k)
                    acc[i][j] = fmaf(qa[i][k], ka[j][k], acc[i][j]);
    }
#pragma unroll
    for (int i = 0; i < 4; ++i)
#pragma unroll
        for (int j = 0; j < 4; ++j)
            acc[i][j] += brow[(n0 + i) * 65 + (m0 + j)];

    float eacc = 0.f;
    int en = 0, em = 0;
    if (t < 129) {
        en = (t < 65) ? 64 : (t - 65);
        em = (t < 65) ? t  : 64;
#pragma unroll 4
        for (int d = 0; d < 64; d += 4) {
            float4 qa4 = *(const float4*)&qs[en][d];
            float4 ka4 = *(const float4*)&ks[em][d];
            eacc += qa4.x * ka4.x + qa4.y * ka4.y + qa4.z * ka4.z + qa4.w * ka4.w;
        }
        eacc += brow[en * 65 + em];
    }
    __syncthreads();

    float (*ps)[68] = qs;
    float (*vsd)[68] = ks;           // ks is dead after this point: reuse as V
#pragma unroll
    for (int i = 0; i < 4; ++i)
#pragma unroll
        for (int j = 0; j < 4; ++j)
            ps[n0 + i][m0 + j] = acc[i][j];
    if (t < 129) ps[en][em] = eacc;
    __syncthreads();

    // softmax rows + stream V into the dead ks slab (load hides under shuffles)
    for (int n = w; n < NT; n += 4) {
        float vv = base[(long)n * 2304 + 1536 + lane];
        float v0 = ps[n][lane];
        float v1 = (lane == 0) ? ps[n][64] : -1e30f;
        float mx = fmaxf(v0, v1);
#pragma unroll
        for (int off = 32; off; off >>= 1) mx = fmaxf(mx, __shfl_xor(mx, off));
        float e0 = __expf(v0 - mx);
        float e1 = (lane == 0) ? __expf(v1 - mx) : 0.f;
        float sm = e0 + e1;
#pragma unroll
        for (int off = 32; off; off >>= 1) sm += __shfl_xor(sm, off);
        float inv = 1.f / sm;
        ps[n][lane] = e0 * inv;
        if (lane == 0) ps[n][64] = e1 * inv;
        vsd[n][lane] = vv;
    }
    __syncthreads();

    const int d0 = tx * 4;
    float o[4][4];
#pragma unroll
    for (int i = 0; i < 4; ++i)
#pragma unroll
        for (int j = 0; j < 4; ++j) o[i][j] = 0.f;

#pragma unroll 2
    for (int m = 0; m < 64; m += 4) {
        float pa[4][4], va[4][4];
#pragma unroll
        for (int i = 0; i < 4; ++i) {
            float4 tmp = *(const float4*)&ps[n0 + i][m];
            pa[i][0] = tmp.x; pa[i][1] = tmp.y; pa[i][2] = tmp.z; pa[i][3] = tmp.w;
        }
#pragma unroll
        for (int jj = 0; jj < 4; ++jj) {
            float4 tmp = *(const float4*)&vsd[m + jj][d0];
            va[jj][0] = tmp.x; va[jj][1] = tmp.y; va[jj][2] = tmp.z; va[jj][3] = tmp.w;
        }
#pragma unroll
        for (int i = 0; i < 4; ++i)
#pragma unroll
            for (int k = 0; k < 4; ++k)
#pragma unroll
                for (int j = 0; j < 4; ++j)
                    o[i][j] = fmaf(pa[i][k], va[k][j], o[i][j]);
    }
#pragma unroll
    for (int i = 0; i < 4; ++i) {
        float p64 = ps[n0 + i][64];
#pragma unroll
        for (int j = 0; j < 4; ++j)
            o[i][j] = fmaf(p64, vsd[64][d0 + j], o[i][j]);
    }

    const long outbase = (long)(b * NT) * 768 + h * 64;
#pragma unroll
    for (int i = 0; i < 4; ++i)
        *(float4*)&attn_out[outbase + (long)(n0 + i) * 768 + d0] =
            make_float4(o[i][0], o[i][1], o[i][2], o[i][3]);

    if (t < 16) {
        const int dd = t * 4;
        float oo0 = 0.f, oo1 = 0.f, oo2 = 0.f, oo3 = 0.f;
        for (int m = 0; m < NT; ++m) {
            float p = ps[64][m];
            oo0 = fmaf(p, vsd[m][dd + 0], oo0);
            oo1 = fmaf(p, vsd[m][dd + 1], oo1);
            oo2 = fmaf(p, vsd[m][dd + 2], oo2);
            oo3 = fmaf(p, vsd[m][dd + 3], oo3);
        }
        *(float4*)&attn_out[outbase + 64L * 768 + dd] = make_float4(oo0, oo1, oo2, oo3);
    }
}

// ---------------------------------------------------------------------------
extern "C" void kernel_launch(void* const* d_in, const int* in_sizes, int n_in,
                              void* d_out, int out_size, void* d_ws, size_t ws_size,
                              hipStream_t stream)
{
    const float* x         = (const float*)d_in[0];
    const float* qkv_w     = (const float*)d_in[1];
    const float* proj_w    = (const float*)d_in[2];
    const float* qn_g      = (const float*)d_in[3];
    const float* qn_b      = (const float*)d_in[4];
    const float* kn_g      = (const float*)d_in[5];
    const float* kn_b      = (const float*)d_in[6];
    const float* sg_w1     = (const float*)d_in[7];
    const float* sg_ln1_g  = (const float*)d_in[8];
    const float* sg_ln1_b  = (const float*)d_in[9];
    const float* sg_w2     = (const float*)d_in[10];
    const float* sg_ln2_g  = (const float*)d_in[11];
    const float* sg_ln2_b  = (const float*)d_in[12];
    const float* sg_bias_w = (const float*)d_in[13];
    float* out = (float*)d_out;

    // Bc=256, 4 chunks. Total workspace = 388 MB (< 527 MB proven available).
    const int Bc = 256, nchunk = 4;
    const long Mq = (long)Bc * NT;          // 16640 rows (=130*128)

    float* ws     = (float*)d_ws;
    float* qkv_c  = ws;                     // 256*65*2304 = 38,338,560 f
    float* bias_c = qkv_c  + 38338560L;     // 256*12*4225 = 12,979,200 f
    float* aout_c = bias_c + 12979200L;     // 256*65*768  = 12,779,520 f
    float* lat1   = aout_c + 12779520L;     // 1024*512
    float* lat2   = lat1   + 524288L;       // 1024*3072
    u16*   P1     = (u16*)(lat2 + 3145728L);// 16640*2304 u16 (x / aout packed)
    u16*   clsp   = P1     + 38338560L;     // 1024*2304
    u16*   lat1p  = clsp   + 2359296L;      // 1024*1536
    u16*   lat2p  = lat1p  + 1572864L;      // 12288*768
    u16*   qkvwp  = lat2p  + 9437184L;      // 2304*2304
    u16*   projwp = qkvwp  + 5308416L;      // 768*2304
    u16*   sgw1p  = projwp + 1769472L;      // 512*2304
    u16*   sgw2p  = sgw1p  + 1179648L;      // 3072*1536
    u16*   sgbwp  = sgw2p  + 4718592L;      // 4225*768

    // ---- pack weights (wmode=1: [hi|lo|hi]) ----
    pack_split<<<(2304 * 192 + 255) / 256, 256, 0, stream>>>(qkv_w, qkvwp, 2304, 768, 768, 1);
    pack_split<<<( 768 * 192 + 255) / 256, 256, 0, stream>>>(proj_w, projwp, 768, 768, 768, 1);
    pack_split<<<( 512 * 192 + 255) / 256, 256, 0, stream>>>(sg_w1, sgw1p, 512, 768, 768, 1);
    pack_split<<<(3072 * 128 + 255) / 256, 256, 0, stream>>>(sg_w2, sgw2p, 3072, 512, 512, 1);
    pack_split<<<(4225 *  64 + 255) / 256, 256, 0, stream>>>(sg_bias_w, sgbwp, 4225, 256, 256, 1);

    // ---- bias MLP (whole batch) ----
    pack_split<<<(1024 * 192 + 255) / 256, 256, 0, stream>>>(x, clsp, 1024, 768, (long)NT * 768, 0);
    gemm_bf16s<<<dim3(512 / 128, 1024 / 128), 256, 0, stream>>>(clsp, sgw1p, lat1, 512, 2304);
    ln_rows<<<1024, 256, 0, stream>>>(lat1, sg_ln1_g, sg_ln1_b, 512, 1);
    pack_split<<<(1024 * 128 + 255) / 256, 256, 0, stream>>>(lat1, lat1p, 1024, 512, 512, 0);
    gemm_bf16s<<<dim3(3072 / 128, 1024 / 128), 256, 0, stream>>>(lat1p, sgw2p, lat2, 3072, 1536);
    ln_rows<<<1024, 256, 0, stream>>>(lat2, sg_ln2_g, sg_ln2_b, 3072, 0);
    pack_split<<<(12288 * 64 + 255) / 256, 256, 0, stream>>>(lat2, lat2p, 12288, 256, 256, 0);

    // ---- per-chunk pipeline ----
    for (int c = 0; c < nchunk; ++c) {
        const float* xc = x + (long)c * Mq * 768;

        // pack x chunk -> P1 (16640 x 2304)
        pack_split<<<(int)((Mq * 192 + 255) / 256), 256, 0, stream>>>(xc, P1, (int)Mq, 768, 768, 0);
        // qkv_c = xc @ qkv_w^T    (16640 x 2304, Kp=2304)
        gemm_bf16s<<<dim3(2304 / 128, (int)(Mq / 128)), 256, 0, stream>>>(P1, qkvwp, qkv_c, 2304, 2304);
        // bias_c = lat2p chunk @ sg_bias_w^T   (3072 x 4225, Kp=768)
        gemm_bf16s<<<dim3((4225 + 127) / 128, 3072 / 128), 256, 0, stream>>>(
            lat2p + (long)c * 3072 * 768, sgbwp, bias_c, 4225, 768);
        // fused attention -> aout_c
        attn_fused<<<Bc * 12, 256, 0, stream>>>(qkv_c, bias_c, qn_g, qn_b, kn_g, kn_b, aout_c);
        // pack aout -> P1 (16640 x 2304)
        pack_split<<<(int)((Mq * 192 + 255) / 256), 256, 0, stream>>>(aout_c, P1, (int)Mq, 768, 768, 0);
        // out chunk = aout @ proj_w^T   (16640 x 768, Kp=2304)
        gemm_bf16s<<<dim3(768 / 128, (int)(Mq / 128)), 256, 0, stream>>>(
            P1, projwp, out + (long)c * Mq * 768, 768, 2304);
    }
}

// Round 5
// 2506.636 us; speedup vs baseline: 2.0410x; 1.1709x over previous
//
#include <hip/hip_runtime.h>
#include <math.h>

// Problem constants (B=1024, N_TOK=65, C=768, H=12, D=64, L=256)
#define NT 65

typedef unsigned short u16;
typedef __attribute__((ext_vector_type(8))) short short8v;
typedef __attribute__((ext_vector_type(4))) float float4v;

__device__ __forceinline__ u16 bf16rn(float f) {
    unsigned int u = __float_as_uint(f);
    u += 0x7FFFu + ((u >> 16) & 1u);
    return (u16)(u >> 16);
}
__device__ __forceinline__ float bf16tof(u16 h) {
    return __uint_as_float(((unsigned int)h) << 16);
}

// async global->LDS, 16B per lane. LDS dest = wave-uniform base + lane*16.
__device__ __forceinline__ void gload16(const void* g, void* l) {
    __builtin_amdgcn_global_load_lds(
        (const __attribute__((address_space(1))) unsigned int*)g,
        (__attribute__((address_space(3))) unsigned int*)l, 16, 0, 0);
}

// ---------------------------------------------------------------------------
// Split-bf16 GEMM: C[M,N] = Ap[M,Kp] @ Wp[N,Kp]^T, fp32 accumulate.
// Ap rows = [hi|hi|lo], Wp rows = [hi|lo|hi]  => fp32-accurate product.
// 128x128 tile, BK=32, 256 thr = 4 waves (2x2 quadrants of 64x64),
// each wave: 4x4 grid of mfma_f32_16x16x32_bf16.
// Requires: M % 128 == 0, Kp % 32 == 0. N ragged (clamped loads, guarded st).
// XCD-aware bijective block swizzle (T1/m204).
// R5: double-buffered single-barrier K-loop (T3 minimum recipe). Stage of
// tile t+1 is issued BEFORE ds_read+MFMA of tile t; the lone __syncthreads
// (whose implicit vmcnt(0) drain previously exposed the full ~900cy load
// latency every K-step) now only waits the remainder. LDS 16->32 KB.
// ---------------------------------------------------------------------------
__global__ __launch_bounds__(256) void gemm_bf16s(
    const u16* __restrict__ Ap, const u16* __restrict__ Wp,
    float* __restrict__ C, int N, int Kp)
{
    __shared__ __align__(16) u16 As[2][128 * 32];
    __shared__ __align__(16) u16 Bs[2][128 * 32];

    const int t = threadIdx.x;
    const int lane = t & 63, w = t >> 6;

    // --- XCD swizzle (bijective for any nwg) ---
    const int nbx = gridDim.x;
    const int nwg = nbx * gridDim.y;
    const int o   = blockIdx.y * nbx + blockIdx.x;     // dispatch-linear id
    const int q8  = nwg >> 3, r8 = nwg & 7;
    const int xcd = o & 7, sl = o >> 3;
    const int logical = (xcd < r8 ? xcd * (q8 + 1)
                                  : r8 * (q8 + 1) + (xcd - r8) * q8) + sl;
    const int bx = logical % nbx, by = logical / nbx;

    const int col0 = bx * 128;
    const long row0 = (long)by * 128;
    const int wm = w >> 1, wn = w & 1;

    float4v acc[4][4];
#pragma unroll
    for (int i = 0; i < 4; ++i)
#pragma unroll
        for (int j = 0; j < 4; ++j)
#pragma unroll
            for (int r = 0; r < 4; ++r) acc[i][j][r] = 0.f;

    // staging: wave w covers rows [w*32, w*32+32); instr p covers 16 rows.
    // lane -> row (lane>>2), k-offset (lane&3)*8 elems; LDS flat = lane*8 elems.
    const int srow = lane >> 2;
    const int skof = (lane & 3) * 8;

    const u16* aG0 = Ap + (row0 + w * 32 + srow) * (long)Kp + skof;
    const u16* aG1 = aG0 + 16 * (long)Kp;
    int bn0 = col0 + w * 32 + srow;      if (bn0 > N - 1) bn0 = N - 1;
    int bn1 = col0 + w * 32 + 16 + srow; if (bn1 > N - 1) bn1 = N - 1;
    const u16* bG0 = Wp + (long)bn0 * Kp + skof;
    const u16* bG1 = Wp + (long)bn1 * Kp + skof;

    // fragment read offset: row (lane&15) of the 16-row tile, k-quad (lane>>4)*8
    const int foff = (lane & 15) * 32 + (lane >> 4) * 8;

    // prologue: stage tile 0 into buffer 0, then one full sync.
    gload16(aG0, &As[0][w * 1024]);
    gload16(aG1, &As[0][w * 1024 + 512]);
    gload16(bG0, &Bs[0][w * 1024]);
    gload16(bG1, &Bs[0][w * 1024 + 512]);
    __syncthreads();

    int cur = 0;
    for (int kt = 0; kt < Kp; kt += 32) {
        // issue next-tile stage FIRST (latency hides under this tile's work)
        if (kt + 32 < Kp) {
            const int nxt = cur ^ 1;
            gload16(aG0 + kt + 32, &As[nxt][w * 1024]);
            gload16(aG1 + kt + 32, &As[nxt][w * 1024 + 512]);
            gload16(bG0 + kt + 32, &Bs[nxt][w * 1024]);
            gload16(bG1 + kt + 32, &Bs[nxt][w * 1024 + 512]);
        }

        const u16* aF = &As[cur][wm * 64 * 32 + foff];
        const u16* bF = &Bs[cur][wn * 64 * 32 + foff];
        short8v a[4], b[4];
#pragma unroll
        for (int i = 0; i < 4; ++i) a[i] = *(const short8v*)(aF + i * 512);
#pragma unroll
        for (int j = 0; j < 4; ++j) b[j] = *(const short8v*)(bF + j * 512);
#pragma unroll
        for (int i = 0; i < 4; ++i)
#pragma unroll
            for (int j = 0; j < 4; ++j)
                acc[i][j] = __builtin_amdgcn_mfma_f32_16x16x32_bf16(
                    a[i], b[j], acc[i][j], 0, 0, 0);

        // single barrier: implicit vmcnt(0)+lgkmcnt(0) drain covers the
        // just-issued next-tile stage AND orders this tile's reads before
        // the buffer is overwritten two iterations from now.
        __syncthreads();
        cur ^= 1;
    }

    // C/D layout: col = lane&15, row = (lane>>4)*4 + reg  [m89/m91 verified]
    const int cn = lane & 15, cq = lane >> 4;
#pragma unroll
    for (int i = 0; i < 4; ++i) {
        const long r0 = row0 + wm * 64 + i * 16 + cq * 4;
#pragma unroll
        for (int j = 0; j < 4; ++j) {
            const int col = col0 + wn * 64 + j * 16 + cn;
            if (col < N) {
#pragma unroll
                for (int r = 0; r < 4; ++r)
                    C[(r0 + r) * (long)N + col] = acc[i][j][r];
            }
        }
    }
}

// ---------------------------------------------------------------------------
// Pack fp32 (M x K, row stride rs) -> bf16 split (M x 3K).
// wmode 0 (A operand): [hi|hi|lo].  wmode 1 (W operand): [hi|lo|hi].
// ---------------------------------------------------------------------------
__global__ __launch_bounds__(256) void pack_split(
    const float* __restrict__ src, u16* __restrict__ dst,
    int M, int K, long rs, int wmode)
{
    const long idx = (long)blockIdx.x * 256 + threadIdx.x;
    const int k4cnt = K >> 2;
    if (idx >= (long)M * k4cnt) return;
    const int m = (int)(idx / k4cnt);
    const int k = (int)(idx % k4cnt) << 2;
    const float4 v = *(const float4*)(src + (long)m * rs + k);
    u16 h0 = bf16rn(v.x), h1 = bf16rn(v.y), h2 = bf16rn(v.z), h3 = bf16rn(v.w);
    u16 l0 = bf16rn(v.x - bf16tof(h0)), l1 = bf16rn(v.y - bf16tof(h1));
    u16 l2 = bf16rn(v.z - bf16tof(h2)), l3 = bf16rn(v.w - bf16tof(h3));
    ushort4 hv = make_ushort4(h0, h1, h2, h3);
    ushort4 lv = make_ushort4(l0, l1, l2, l3);
    u16* drow = dst + (long)m * (3 * K);
    *(ushort4*)(drow + k) = hv;
    *(ushort4*)(drow + K + k) = wmode ? lv : hv;
    *(ushort4*)(drow + 2 * K + k) = wmode ? hv : lv;
}

// ---------------------------------------------------------------------------
// Row LayerNorm (+ optional SiLU), in place. One block per row, 256 threads.
// ---------------------------------------------------------------------------
__global__ __launch_bounds__(256) void ln_rows(
    float* __restrict__ data, const float* __restrict__ g,
    const float* __restrict__ b, int ncols, int do_silu)
{
    const int row = blockIdx.x;
    const int t = threadIdx.x;
    float* drow = data + (long)row * ncols;

    float sum = 0.f, sumsq = 0.f;
    for (int c = t; c < ncols; c += 256) {
        float x = drow[c];
        sum += x; sumsq += x * x;
    }
#pragma unroll
    for (int off = 32; off; off >>= 1) {
        sum   += __shfl_xor(sum, off);
        sumsq += __shfl_xor(sumsq, off);
    }
    __shared__ float red[2][4];
    const int lane = t & 63, w = t >> 6;
    if (lane == 0) { red[0][w] = sum; red[1][w] = sumsq; }
    __syncthreads();
    sum   = red[0][0] + red[0][1] + red[0][2] + red[0][3];
    sumsq = red[1][0] + red[1][1] + red[1][2] + red[1][3];

    const float inv = 1.f / (float)ncols;
    const float mu  = sum * inv;
    const float var = sumsq * inv - mu * mu;
    const float r   = rsqrtf(var + 1e-5f);
    for (int c = t; c < ncols; c += 256) {
        float y = (drow[c] - mu) * r * g[c] + b[c];
        if (do_silu) y = y / (1.f + expf(-y));
        drow[c] = y;
    }
}

// ---------------------------------------------------------------------------
// Fused attention.
// R4 (confirmed): unroll-2 on the d/m loops + amdgpu_waves_per_eu(3) killed
// the spill (dur 575 -> ~170). Remaining known inefficiency: the QK ka reads
// ks[m0+j][d] with m0=tx*4 put 16 lanes on 2 bank-groups (4-row stride =
// 1088B = 16 dwords mod 32) -> 8-way conflict, SQ_LDS_BANK_CONFLICT pinned
// at 9.5M/dispatch all session.
// R5: remap the m-tiling from (tx*4 + j) to (tx + 16*j). Lane stride becomes
// 1 row = 272B = 4 banks -> 2 lanes/bank-group = free. Bias-add and P-write
// indices remapped to match; every downstream read (softmax, PV, edge) is by
// absolute index so numerics are identical.
// ---------------------------------------------------------------------------
__global__ __launch_bounds__(256) __attribute__((amdgpu_waves_per_eu(3)))
void attn_fused(
    const float* __restrict__ qkv,   // (Bc*65, 2304)
    const float* __restrict__ bias,  // (Bc*12, 4225)
    const float* __restrict__ qn_g, const float* __restrict__ qn_b,
    const float* __restrict__ kn_g, const float* __restrict__ kn_b,
    float* __restrict__ attn_out)    // (Bc*65, 768)
{
    __shared__ __align__(16) float qs[NT][68];   // later aliased as P
    __shared__ __align__(16) float ks[NT][68];   // later aliased as V

    const int bh = blockIdx.x;
    const int b = bh / 12, h = bh % 12;
    const int t = threadIdx.x, lane = t & 63, w = t >> 6;
    const float scale = 0.125f;      // 64^-0.5

    const float qg = qn_g[lane], qb = qn_b[lane];
    const float kg = kn_g[lane], kb = kn_b[lane];
    const float* base = qkv + (long)(b * NT) * 2304 + h * 64;

    for (int n = w; n < NT; n += 4) {
        const float* row = base + (long)n * 2304;
        float qv = row[lane];
        float kv = row[768 + lane];

        float s = qv;
#pragma unroll
        for (int off = 32; off; off >>= 1) s += __shfl_xor(s, off);
        float mu = s * (1.f / 64.f);
        float dq = qv - mu;
        float s2 = dq * dq;
#pragma unroll
        for (int off = 32; off; off >>= 1) s2 += __shfl_xor(s2, off);
        qs[n][lane] = (dq * rsqrtf(s2 * (1.f / 64.f) + 1e-5f) * qg + qb) * scale;

        s = kv;
#pragma unroll
        for (int off = 32; off; off >>= 1) s += __shfl_xor(s, off);
        mu = s * (1.f / 64.f);
        float dk = kv - mu;
        s2 = dk * dk;
#pragma unroll
        for (int off = 32; off; off >>= 1) s2 += __shfl_xor(s2, off);
        ks[n][lane] = dk * rsqrtf(s2 * (1.f / 64.f) + 1e-5f) * kg + kb;
    }
    __syncthreads();

    const int tx = t & 15, ty = t >> 4;
    const int n0 = ty * 4;
    const float* brow = bias + (long)bh * 4225;

    float acc[4][4];                 // acc[i][j] <-> S[n0+i][tx + 16*j]
#pragma unroll
    for (int i = 0; i < 4; ++i)
#pragma unroll
        for (int j = 0; j < 4; ++j) acc[i][j] = 0.f;

#pragma unroll 2
    for (int d = 0; d < 64; d += 4) {
        float qa[4][4], ka[4][4];
#pragma unroll
        for (int i = 0; i < 4; ++i) {
            float4 tmp = *(const float4*)&qs[n0 + i][d];
            qa[i][0] = tmp.x; qa[i][1] = tmp.y; qa[i][2] = tmp.z; qa[i][3] = tmp.w;
        }
#pragma unroll
        for (int j = 0; j < 4; ++j) {
            float4 tmp = *(const float4*)&ks[tx + 16 * j][d];
            ka[j][0] = tmp.x; ka[j][1] = tmp.y; ka[j][2] = tmp.z; ka[j][3] = tmp.w;
        }
#pragma unroll
        for (int i = 0; i < 4; ++i)
#pragma unroll
            for (int j = 0; j < 4; ++j)
#pragma unroll
                for (int k = 0; k < 4; ++k)
                    acc[i][j] = fmaf(qa[i][k], ka[j][k], acc[i][j]);
    }
#pragma unroll
    for (int i = 0; i < 4; ++i)
#pragma unroll
        for (int j = 0; j < 4; ++j)
            acc[i][j] += brow[(n0 + i) * 65 + tx + 16 * j];

    float eacc = 0.f;
    int en = 0, em = 0;
    if (t < 129) {
        en = (t < 65) ? 64 : (t - 65);
        em = (t < 65) ? t  : 64;
#pragma unroll 4
        for (int d = 0; d < 64; d += 4) {
            float4 qa4 = *(const float4*)&qs[en][d];
            float4 ka4 = *(const float4*)&ks[em][d];
            eacc += qa4.x * ka4.x + qa4.y * ka4.y + qa4.z * ka4.z + qa4.w * ka4.w;
        }
        eacc += brow[en * 65 + em];
    }
    __syncthreads();

    float (*ps)[68] = qs;
    float (*vsd)[68] = ks;           // ks is dead after this point: reuse as V
#pragma unroll
    for (int i = 0; i < 4; ++i)
#pragma unroll
        for (int j = 0; j < 4; ++j)
            ps[n0 + i][tx + 16 * j] = acc[i][j];
    if (t < 129) ps[en][em] = eacc;
    __syncthreads();

    // softmax rows + stream V into the dead ks slab (load hides under shuffles)
    for (int n = w; n < NT; n += 4) {
        float vv = base[(long)n * 2304 + 1536 + lane];
        float v0 = ps[n][lane];
        float v1 = (lane == 0) ? ps[n][64] : -1e30f;
        float mx = fmaxf(v0, v1);
#pragma unroll
        for (int off = 32; off; off >>= 1) mx = fmaxf(mx, __shfl_xor(mx, off));
        float e0 = __expf(v0 - mx);
        float e1 = (lane == 0) ? __expf(v1 - mx) : 0.f;
        float sm = e0 + e1;
#pragma unroll
        for (int off = 32; off; off >>= 1) sm += __shfl_xor(sm, off);
        float inv = 1.f / sm;
        ps[n][lane] = e0 * inv;
        if (lane == 0) ps[n][64] = e1 * inv;
        vsd[n][lane] = vv;
    }
    __syncthreads();

    const int d0 = tx * 4;
    float o[4][4];
#pragma unroll
    for (int i = 0; i < 4; ++i)
#pragma unroll
        for (int j = 0; j < 4; ++j) o[i][j] = 0.f;

#pragma unroll 2
    for (int m = 0; m < 64; m += 4) {
        float pa[4][4], va[4][4];
#pragma unroll
        for (int i = 0; i < 4; ++i) {
            float4 tmp = *(const float4*)&ps[n0 + i][m];
            pa[i][0] = tmp.x; pa[i][1] = tmp.y; pa[i][2] = tmp.z; pa[i][3] = tmp.w;
        }
#pragma unroll
        for (int jj = 0; jj < 4; ++jj) {
            float4 tmp = *(const float4*)&vsd[m + jj][d0];
            va[jj][0] = tmp.x; va[jj][1] = tmp.y; va[jj][2] = tmp.z; va[jj][3] = tmp.w;
        }
#pragma unroll
        for (int i = 0; i < 4; ++i)
#pragma unroll
            for (int k = 0; k < 4; ++k)
#pragma unroll
                for (int j = 0; j < 4; ++j)
                    o[i][j] = fmaf(pa[i][k], va[k][j], o[i][j]);
    }
#pragma unroll
    for (int i = 0; i < 4; ++i) {
        float p64 = ps[n0 + i][64];
#pragma unroll
        for (int j = 0; j < 4; ++j)
            o[i][j] = fmaf(p64, vsd[64][d0 + j], o[i][j]);
    }

    const long outbase = (long)(b * NT) * 768 + h * 64;
#pragma unroll
    for (int i = 0; i < 4; ++i)
        *(float4*)&attn_out[outbase + (long)(n0 + i) * 768 + d0] =
            make_float4(o[i][0], o[i][1], o[i][2], o[i][3]);

    if (t < 16) {
        const int dd = t * 4;
        float oo0 = 0.f, oo1 = 0.f, oo2 = 0.f, oo3 = 0.f;
        for (int m = 0; m < NT; ++m) {
            float p = ps[64][m];
            oo0 = fmaf(p, vsd[m][dd + 0], oo0);
            oo1 = fmaf(p, vsd[m][dd + 1], oo1);
            oo2 = fmaf(p, vsd[m][dd + 2], oo2);
            oo3 = fmaf(p, vsd[m][dd + 3], oo3);
        }
        *(float4*)&attn_out[outbase + 64L * 768 + dd] = make_float4(oo0, oo1, oo2, oo3);
    }
}

// ---------------------------------------------------------------------------
extern "C" void kernel_launch(void* const* d_in, const int* in_sizes, int n_in,
                              void* d_out, int out_size, void* d_ws, size_t ws_size,
                              hipStream_t stream)
{
    const float* x         = (const float*)d_in[0];
    const float* qkv_w     = (const float*)d_in[1];
    const float* proj_w    = (const float*)d_in[2];
    const float* qn_g      = (const float*)d_in[3];
    const float* qn_b      = (const float*)d_in[4];
    const float* kn_g      = (const float*)d_in[5];
    const float* kn_b      = (const float*)d_in[6];
    const float* sg_w1     = (const float*)d_in[7];
    const float* sg_ln1_g  = (const float*)d_in[8];
    const float* sg_ln1_b  = (const float*)d_in[9];
    const float* sg_w2     = (const float*)d_in[10];
    const float* sg_ln2_g  = (const float*)d_in[11];
    const float* sg_ln2_b  = (const float*)d_in[12];
    const float* sg_bias_w = (const float*)d_in[13];
    float* out = (float*)d_out;

    // Bc=256, 4 chunks. Total workspace = 388 MB (< 527 MB proven available).
    const int Bc = 256, nchunk = 4;
    const long Mq = (long)Bc * NT;          // 16640 rows (=130*128)

    float* ws     = (float*)d_ws;
    float* qkv_c  = ws;                     // 256*65*2304 = 38,338,560 f
    float* bias_c = qkv_c  + 38338560L;     // 256*12*4225 = 12,979,200 f
    float* aout_c = bias_c + 12979200L;     // 256*65*768  = 12,779,520 f
    float* lat1   = aout_c + 12779520L;     // 1024*512
    float* lat2   = lat1   + 524288L;       // 1024*3072
    u16*   P1     = (u16*)(lat2 + 3145728L);// 16640*2304 u16 (x / aout packed)
    u16*   clsp   = P1     + 38338560L;     // 1024*2304
    u16*   lat1p  = clsp   + 2359296L;      // 1024*1536
    u16*   lat2p  = lat1p  + 1572864L;      // 12288*768
    u16*   qkvwp  = lat2p  + 9437184L;      // 2304*2304
    u16*   projwp = qkvwp  + 5308416L;      // 768*2304
    u16*   sgw1p  = projwp + 1769472L;      // 512*2304
    u16*   sgw2p  = sgw1p  + 1179648L;      // 3072*1536
    u16*   sgbwp  = sgw2p  + 4718592L;      // 4225*768

    // ---- pack weights (wmode=1: [hi|lo|hi]) ----
    pack_split<<<(2304 * 192 + 255) / 256, 256, 0, stream>>>(qkv_w, qkvwp, 2304, 768, 768, 1);
    pack_split<<<( 768 * 192 + 255) / 256, 256, 0, stream>>>(proj_w, projwp, 768, 768, 768, 1);
    pack_split<<<( 512 * 192 + 255) / 256, 256, 0, stream>>>(sg_w1, sgw1p, 512, 768, 768, 1);
    pack_split<<<(3072 * 128 + 255) / 256, 256, 0, stream>>>(sg_w2, sgw2p, 3072, 512, 512, 1);
    pack_split<<<(4225 *  64 + 255) / 256, 256, 0, stream>>>(sg_bias_w, sgbwp, 4225, 256, 256, 1);

    // ---- bias MLP (whole batch) ----
    pack_split<<<(1024 * 192 + 255) / 256, 256, 0, stream>>>(x, clsp, 1024, 768, (long)NT * 768, 0);
    gemm_bf16s<<<dim3(512 / 128, 1024 / 128), 256, 0, stream>>>(clsp, sgw1p, lat1, 512, 2304);
    ln_rows<<<1024, 256, 0, stream>>>(lat1, sg_ln1_g, sg_ln1_b, 512, 1);
    pack_split<<<(1024 * 128 + 255) / 256, 256, 0, stream>>>(lat1, lat1p, 1024, 512, 512, 0);
    gemm_bf16s<<<dim3(3072 / 128, 1024 / 128), 256, 0, stream>>>(lat1p, sgw2p, lat2, 3072, 1536);
    ln_rows<<<1024, 256, 0, stream>>>(lat2, sg_ln2_g, sg_ln2_b, 3072, 0);
    pack_split<<<(12288 * 64 + 255) / 256, 256, 0, stream>>>(lat2, lat2p, 12288, 256, 256, 0);

    // ---- per-chunk pipeline ----
    for (int c = 0; c < nchunk; ++c) {
        const float* xc = x + (long)c * Mq * 768;

        // pack x chunk -> P1 (16640 x 2304)
        pack_split<<<(int)((Mq * 192 + 255) / 256), 256, 0, stream>>>(xc, P1, (int)Mq, 768, 768, 0);
        // qkv_c = xc @ qkv_w^T    (16640 x 2304, Kp=2304)
        gemm_bf16s<<<dim3(2304 / 128, (int)(Mq / 128)), 256, 0, stream>>>(P1, qkvwp, qkv_c, 2304, 2304);
        // bias_c = lat2p chunk @ sg_bias_w^T   (3072 x 4225, Kp=768)
        gemm_bf16s<<<dim3((4225 + 127) / 128, 3072 / 128), 256, 0, stream>>>(
            lat2p + (long)c * 3072 * 768, sgbwp, bias_c, 4225, 768);
        // fused attention -> aout_c
        attn_fused<<<Bc * 12, 256, 0, stream>>>(qkv_c, bias_c, qn_g, qn_b, kn_g, kn_b, aout_c);
        // pack aout -> P1 (16640 x 2304)
        pack_split<<<(int)((Mq * 192 + 255) / 256), 256, 0, stream>>>(aout_c, P1, (int)Mq, 768, 768, 0);
        // out chunk = aout @ proj_w^T   (16640 x 768, Kp=2304)
        gemm_bf16s<<<dim3(768 / 128, (int)(Mq / 128)), 256, 0, stream>>>(
            P1, projwp, out + (long)c * Mq * 768, 768, 2304);
    }
}